// Round 7
// baseline (212.190 us; speedup 1.0000x reference)
//
#include <hip/hip_runtime.h>
#include <math.h>

// Problem constants (from reference)
#define Bb   8
#define Qq   64
#define Kk   256
#define Dd   256
#define Nn   (Bb * Qq)          // 512
#define GNi  0.0625f            // 1/GN
#define EPSf 1e-5f

// ---------------------------------------------------------------------------
// 64-lane wave reduction (sum), result broadcast to all lanes
__device__ __forceinline__ float wred(float x) {
#pragma unroll
    for (int off = 32; off > 0; off >>= 1)
        x += __shfl_xor(x, off, 64);
    return x;
}

// ---------------------------------------------------------------------------
// 64x64 GEMM tile core, R regions sharing one A tile. 256 threads.
// A: 64 rows, leading dim lda. B_r: K x 256 weight matrices, col window bn.
// acc[r][i*4+j]: thread (ty,tx) owns rows ty*4+i, cols tx*4+j.
// As k-major [16][68]; Ws_r [16][68]. Register-prefetched staging.
template<int R>
__device__ __forceinline__ void gemm64(
    const float* __restrict__ A, int lda,
    const float* __restrict__ B0, const float* __restrict__ B1,
    const float* __restrict__ B2, const float* __restrict__ B3,
    int bn, int Kc, float (&acc)[R][16], float* As, float* Ws)
{
    const int tid = threadIdx.x;
    const int aRow = tid >> 2, aCol = (tid & 3) * 4;
    const int wr = tid >> 4, wcb = (tid & 15) * 4;
    const int ty = tid >> 4, tx = tid & 15;
    const float* Bp[4] = {B0, B1, B2, B3};

    float4 rA = *(const float4*)(A + (size_t)aRow * lda + aCol);
    float4 rW[R];
#pragma unroll
    for (int r = 0; r < R; ++r)
        rW[r] = *(const float4*)(Bp[r] + (size_t)wr * 256 + bn + wcb);

    for (int k0 = 0; k0 < Kc; k0 += 16) {
        __syncthreads();
        As[(aCol + 0) * 68 + aRow] = rA.x;
        As[(aCol + 1) * 68 + aRow] = rA.y;
        As[(aCol + 2) * 68 + aRow] = rA.z;
        As[(aCol + 3) * 68 + aRow] = rA.w;
#pragma unroll
        for (int r = 0; r < R; ++r)
            *(float4*)&Ws[r * 1088 + wr * 68 + wcb] = rW[r];
        __syncthreads();
        if (k0 + 16 < Kc) {
            rA = *(const float4*)(A + (size_t)aRow * lda + k0 + 16 + aCol);
#pragma unroll
            for (int r = 0; r < R; ++r)
                rW[r] = *(const float4*)(Bp[r] + (size_t)(k0 + 16 + wr) * 256 + bn + wcb);
        }
#pragma unroll
        for (int kk = 0; kk < 16; ++kk) {
            const float4 a4 = *(const float4*)&As[kk * 68 + ty * 4];
            const float av[4] = {a4.x, a4.y, a4.z, a4.w};
#pragma unroll
            for (int r = 0; r < R; ++r) {
                const float4 b4 = *(const float4*)&Ws[r * 1088 + kk * 68 + tx * 4];
                const float bw[4] = {b4.x, b4.y, b4.z, b4.w};
#pragma unroll
                for (int i = 0; i < 4; ++i)
#pragma unroll
                    for (int j = 0; j < 4; ++j)
                        acc[r][i * 4 + j] = fmaf(av[i], bw[j], acc[r][i * 4 + j]);
            }
        }
    }
}

// ---------------------------------------------------------------------------
// L1 prep: 81 blocks, no inter-dependencies.
//  id <32 : cond = query @ W_cond (512x256)
//  id <48 : Wg = W_gk1 @ W_gk2   (256x256, K=16)
//  id <80 : KVr = keyval @ W_router (2048x4)
//  id ==80: KVq8 = keyval[:,255,:] @ W_q (8x256)
__global__ __launch_bounds__(256) void prep(
    const float* __restrict__ query, const float* __restrict__ keyval,
    const float* __restrict__ W_cond, const float* __restrict__ Wg1,
    const float* __restrict__ Wg2, const float* __restrict__ Wr,
    const float* __restrict__ Wq,
    float* __restrict__ cond, float* __restrict__ Wg,
    float* __restrict__ KVr, float* __restrict__ KVq8)
{
    __shared__ float lds[2 * 1088];
    const int id = blockIdx.x;
    const int tid = threadIdx.x;

    if (id < 48) {
        float acc[1][16] = {};
        const int ty = tid >> 4, tx = tid & 15;
        if (id < 32) {
            const int bm = (id >> 2) * 64, bn = (id & 3) * 64;
            gemm64<1>(query + (size_t)bm * Dd, Dd, W_cond, nullptr, nullptr, nullptr,
                      bn, Dd, acc, lds, lds + 1088);
#pragma unroll
            for (int i = 0; i < 4; ++i)
                *(float4*)&cond[(size_t)(bm + ty * 4 + i) * Dd + bn + tx * 4] =
                    make_float4(acc[0][i * 4 + 0], acc[0][i * 4 + 1],
                                acc[0][i * 4 + 2], acc[0][i * 4 + 3]);
        } else {
            const int id3 = id - 32;
            const int bm = (id3 >> 2) * 64, bn = (id3 & 3) * 64;
            gemm64<1>(Wg1 + (size_t)bm * 16, 16, Wg2, nullptr, nullptr, nullptr,
                      bn, 16, acc, lds, lds + 1088);
#pragma unroll
            for (int i = 0; i < 4; ++i)
                *(float4*)&Wg[(size_t)(bm + ty * 4 + i) * Dd + bn + tx * 4] =
                    make_float4(acc[0][i * 4 + 0], acc[0][i * 4 + 1],
                                acc[0][i * 4 + 2], acc[0][i * 4 + 3]);
        }
        return;
    }
    if (id < 80) {    // KVr: 32 blocks x 256 threads = 8192 = 2048x4
        const int idx = (id - 48) * 256 + tid;
        const int row = idx >> 2, col = idx & 3;
        float a = 0.f;
        for (int k = 0; k < 256; ++k)
            a = fmaf(keyval[(size_t)row * Dd + k], Wr[(size_t)k * 4 + col], a);
        KVr[idx] = a;
        return;
    }
    // KVq8: stage last keyval row of each batch, then dot with W_q col tid
    for (int b8 = 0; b8 < 8; ++b8)
        lds[b8 * 256 + tid] = keyval[((size_t)b8 * Kk + 255) * Dd + tid];
    __syncthreads();
    float a8[8] = {};
    for (int k = 0; k < 256; ++k) {
        const float wq = Wq[(size_t)k * Dd + tid];
#pragma unroll
        for (int b8 = 0; b8 < 8; ++b8)
            a8[b8] = fmaf(lds[b8 * 256 + k], wq, a8[b8]);
    }
    for (int b8 = 0; b8 < 8; ++b8)
        KVq8[b8 * 256 + tid] = a8[b8];
}

// ---------------------------------------------------------------------------
// L2 main: 168 blocks (needs cond, Wg).
//  id <128 : KVi[row][c] = {k,v,pre,0}, 3-region blocks over keyval
//  id <160 : Cbi[n][c] = {q,k,v,pre}, 4-region blocks over cond
//  id <168 : Cr = cond @ W_router (512x4)
__global__ __launch_bounds__(256) void maingemm(
    const float* __restrict__ keyval, const float* __restrict__ cond,
    const float* __restrict__ Wq, const float* __restrict__ Wk,
    const float* __restrict__ Wv, const float* __restrict__ Wg,
    const float* __restrict__ Wr,
    float* __restrict__ KVi, float* __restrict__ Cbi, float* __restrict__ Cr)
{
    __shared__ float lds[5 * 1088];
    const int id = blockIdx.x;
    const int tid = threadIdx.x;
    const int ty = tid >> 4, tx = tid & 15;

    if (id < 128) {
        const int bm = (id >> 2) * 64;
        const int bn = (id & 3) * 64;
        float acc[3][16] = {};
        gemm64<3>(keyval + (size_t)bm * Dd, Dd, Wk, Wv, Wg, nullptr,
                  bn, Dd, acc, lds, lds + 1088);
#pragma unroll
        for (int i = 0; i < 4; ++i) {
            const size_t rowo = (size_t)(bm + ty * 4 + i) * 1024;
#pragma unroll
            for (int j = 0; j < 4; ++j)
                *(float4*)&KVi[rowo + (size_t)(bn + tx * 4 + j) * 4] =
                    make_float4(acc[0][i * 4 + j], acc[1][i * 4 + j],
                                acc[2][i * 4 + j], 0.f);
        }
    } else if (id < 160) {
        const int id2 = id - 128;
        const int bm = (id2 >> 2) * 64;
        const int bn = (id2 & 3) * 64;
        float acc[4][16] = {};
        gemm64<4>(cond + (size_t)bm * Dd, Dd, Wq, Wk, Wv, Wg,
                  bn, Dd, acc, lds, lds + 1088);
#pragma unroll
        for (int i = 0; i < 4; ++i) {
            const size_t rowo = (size_t)(bm + ty * 4 + i) * 1024;
#pragma unroll
            for (int j = 0; j < 4; ++j)
                *(float4*)&Cbi[rowo + (size_t)(bn + tx * 4 + j) * 4] =
                    make_float4(acc[0][i * 4 + j], acc[1][i * 4 + j],
                                acc[2][i * 4 + j], acc[3][i * 4 + j]);
        }
    } else {          // Cr: 8 blocks x 256 = 2048 = 512x4
        const int idx = (id - 160) * 256 + tid;
        const int row = idx >> 2, col = idx & 3;
        float a = 0.f;
        for (int k = 0; k < 256; ++k)
            a = fmaf(cond[(size_t)row * Dd + k], Wr[(size_t)k * 4 + col], a);
        Cr[idx] = a;
    }
}

// ---------------------------------------------------------------------------
// One 8-t tile of the reverse recurrence: phase A from registers (buf),
// phase B wave-local LDS transpose-reduce.
__device__ __forceinline__ void tile_step8(
    const float4* buf, int thi, const float* mfs, const float4* wm,
    float ql, float kc, float vc, float pc,
    float& E0, float& E1, float& E2, float& E3, float& E4, float& o,
    float (*Pt)[68], float* sb, int lane, int tl, int qq)
{
    float vreg[8];
#pragma unroll
    for (int i = 0; i < 8; ++i) {
        const int t = thi - i;
        const float mf = mfs[t];
        const float4 kv = buf[i];
        const float kkv = (kv.x + kc) * mf;
        vreg[i] = (kv.y + vc) * mf;
        const float pre = kv.z + pc;
        const float4 w = wm[t];
        const float ls = fminf(pre, 0.f) - __logf(1.f + __expf(-fabsf(pre)));
        float dg = __expf(ls * GNi);
        dg = (mf != 0.f) ? dg : 1.f;
        const float zf = (E0 + w.x * E1) + (w.y * E2 + w.z * E3) + w.w * E4;
        Pt[i][lane] = ql * kkv * zf;
        E0 *= dg;
        E1 *= (w.x > 0.f) ? dg : 1.f;
        E2 *= (w.y > 0.f) ? dg : 1.f;
        E3 *= (w.z > 0.f) ? dg : 1.f;
        E4 *= (w.w > 0.f) ? dg : 1.f;
    }
    __builtin_amdgcn_wave_barrier();
    // s[tl] = sum_c Pt[tl][c]; lane -> (tl = t-idx, qq = c-octet)
    const float4 p0 = *(const float4*)&Pt[tl][qq * 8];
    const float4 p1 = *(const float4*)&Pt[tl][qq * 8 + 4];
    float s = ((p0.x + p0.y) + (p0.z + p0.w)) + ((p1.x + p1.y) + (p1.z + p1.w));
    s += __shfl_xor(s, 8, 64);
    s += __shfl_xor(s, 16, 64);
    s += __shfl_xor(s, 32, 64);
    sb[tl] = s;                       // same-value multi-write, benign
    __builtin_amdgcn_wave_barrier();
    const float4 s0 = *(const float4*)&sb[0];
    const float4 s1 = *(const float4*)&sb[4];
    o = fmaf(s0.x, vreg[0], o); o = fmaf(s0.y, vreg[1], o);
    o = fmaf(s0.z, vreg[2], o); o = fmaf(s0.w, vreg[3], o);
    o = fmaf(s1.x, vreg[4], o); o = fmaf(s1.y, vreg[5], o);
    o = fmaf(s1.z, vreg[6], o); o = fmaf(s1.w, vreg[7], o);
}

// ---------------------------------------------------------------------------
// Fused router + recurrence + RMSNorm + W_o projection. One block per n.
// XCD swizzle: bi -> n = (bi&7)*64 + (bi>>3), so all blocks of a batch b
// land on the same XCD (L2 locality for the shared KVi slice).
__global__ __launch_bounds__(256, 2) void mom_fused(
    const float4* __restrict__ KVi, const float* __restrict__ KVr,
    const float4* __restrict__ Cbi, const float* __restrict__ Cr,
    const float* __restrict__ KVq8, const float* __restrict__ b_gk2,
    const int* __restrict__ mask, const float* __restrict__ W_o,
    const float* __restrict__ norm_w,
    float* __restrict__ out, float* __restrict__ logits)
{
    __shared__ __align__(16) float4 wm[Kk];
    __shared__ __align__(16) float  mfs[Kk];
    __shared__ __align__(16) float  Ptile[4][8][68];
    __shared__ __align__(16) float  sbuf[4][8];
    __shared__ __align__(16) float  onorm[Dd];

    const int bi = blockIdx.x;
    const int n = (bi & 7) * 64 + (bi >> 3);
    const int b = bi & 7;             // = n >> 6
    const int j = threadIdx.x;
    const int lane = j & 63;
    const int wv = j >> 6;

    // cond-side values (interleaved)
    const float4 c4 = Cbi[(size_t)n * 256 + j];
    const float qc = c4.x, kc = c4.y, vc = c4.z;
    const float pc = c4.w + b_gk2[j];
    const float ql = KVq8[b * 256 + j] + qc;

    // ---- router top-2 for t = j; also stage mask as float
    {
        mfs[j] = (float)mask[b * Kk + j];
        const float4 kvr = *(const float4*)&KVr[(size_t)(b * Kk + j) * 4];
        const float4 cr  = *(const float4*)&Cr[(size_t)n * 4];
        float l[4] = {kvr.x + cr.x, kvr.y + cr.y, kvr.z + cr.z, kvr.w + cr.w};
        *(float4*)(logits + ((size_t)n * Kk + j) * 4) =
            make_float4(l[0], l[1], l[2], l[3]);

        int i1 = 0;
#pragma unroll
        for (int q = 1; q < 4; ++q) if (l[q] > l[i1]) i1 = q;
        int i2 = -1;
#pragma unroll
        for (int q = 0; q < 4; ++q) {
            if (q == i1) continue;
            if (i2 < 0 || l[q] > l[i2]) i2 = q;
        }
        const float mx = fmaxf(l[i1], l[i2]);
        const float e1 = __expf(l[i1] - mx);
        const float e2 = __expf(l[i2] - mx);
        const float inv = 1.f / (e1 + e2);
        float w[4] = {0.f, 0.f, 0.f, 0.f};
        w[i1] = e1 * inv;
        w[i2] = e2 * inv;
        wm[j] = make_float4(w[0], w[1], w[2], w[3]);
    }
    __syncthreads();

    const float4* pkv = KVi + (size_t)b * Kk * 256 + j;

    float E0 = 1.f, E1 = 1.f, E2 = 1.f, E3 = 1.f, E4 = 1.f;
    float o = 0.f;
    const int tl = lane & 7, qq = lane >> 3;

    float4 bufA[8], bufB[8];
#pragma unroll
    for (int i = 0; i < 8; ++i) bufA[i] = pkv[(size_t)(255 - i) * 256];

    for (int p = 0; p < 16; ++p) {
        const int tA = 255 - 16 * p;
        const int tB = tA - 8;
#pragma unroll
        for (int i = 0; i < 8; ++i) bufB[i] = pkv[(size_t)(tB - i) * 256];
        tile_step8(bufA, tA, mfs, wm, ql, kc, vc, pc,
                   E0, E1, E2, E3, E4, o, Ptile[wv], sbuf[wv], lane, tl, qq);
        if (p < 15) {
#pragma unroll
            for (int i = 0; i < 8; ++i) bufA[i] = pkv[(size_t)(tB - 8 - i) * 256];
        }
        tile_step8(bufB, tB, mfs, wm, ql, kc, vc, pc,
                   E0, E1, E2, E3, E4, o, Ptile[wv], sbuf[wv], lane, tl, qq);
    }

    // ---- fused RMSNorm over DV (per head = per wave)
    const float ms = wred(o * o) * (1.0f / 64.0f);
    onorm[j] = o * rsqrtf(ms + EPSf) * norm_w[lane];
    __syncthreads();

    // ---- fused output projection: out[n,j] = onorm . W_o[:,j]
    float acc = 0.f;
#pragma unroll 8
    for (int k = 0; k < Dd; ++k)
        acc = fmaf(onorm[k], W_o[(size_t)k * Dd + j], acc);
    out[(size_t)n * Dd + j] = acc;
}

// ---------------------------------------------------------------------------
extern "C" void kernel_launch(void* const* d_in, const int* in_sizes, int n_in,
                              void* d_out, int out_size, void* d_ws, size_t ws_size,
                              hipStream_t stream)
{
    const float* query    = (const float*)d_in[0];   // (8,64,256)
    const float* keyval   = (const float*)d_in[1];   // (8,256,256)
    const int*   mask     = (const int*)  d_in[2];   // (8,256)
    const float* W_cond   = (const float*)d_in[3];   // (256,256)
    const float* W_q      = (const float*)d_in[4];   // (256,256)
    const float* W_k      = (const float*)d_in[5];   // (256,256)
    const float* W_v      = (const float*)d_in[6];   // (256,256)
    const float* W_gk1    = (const float*)d_in[7];   // (256,16)
    const float* W_gk2    = (const float*)d_in[8];   // (16,256)
    const float* b_gk2    = (const float*)d_in[9];   // (256,)
    const float* W_router = (const float*)d_in[10];  // (256,4)
    const float* norm_w   = (const float*)d_in[11];  // (64,)
    const float* W_o      = (const float*)d_in[12];  // (256,256)

    float* out    = (float*)d_out;        // (8,64,256) = 131072
    float* logits = out + Nn * Dd;        // (N*K, 4)   = 524288

    // workspace layout (floats)
    float* p = (float*)d_ws;
    float* Wg   = p; p += Dd * Dd;                  // 65536
    float* cond = p; p += Nn * Dd;                  // 131072
    float* KVi  = p; p += (size_t)Bb * Kk * 1024;   // 2097152 {k,v,pre,0}
    float* KVr  = p; p += Bb * Kk * 4;              // 8192
    float* Cbi  = p; p += (size_t)Nn * 1024;        // 524288 {q,k,v,pre}
    float* Cr   = p; p += Nn * 4;                   // 2048
    float* KVq8 = p; p += Bb * Dd;                  // 2048

    // L1: cond, Wg, KVr, KVq8 (all independent)
    prep<<<81, dim3(256), 0, stream>>>(
        query, keyval, W_cond, W_gk1, W_gk2, W_router, W_q,
        cond, Wg, KVr, KVq8);

    // L2: KVi (keyval-side, 3 regions/block), Cbi (cond-side, 4 regions), Cr
    maingemm<<<168, dim3(256), 0, stream>>>(
        keyval, cond, W_q, W_k, W_v, Wg, W_router, KVi, Cbi, Cr);

    // L3: router + recurrence + RMSNorm + output projection
    mom_fused<<<Nn, dim3(256), 0, stream>>>(
        (const float4*)KVi, KVr, (const float4*)Cbi, Cr,
        KVq8, b_gk2, mask, W_o, norm_w, out, logits);
}

// Round 8
// 209.687 us; speedup vs baseline: 1.0119x; 1.0119x over previous
//
#include <hip/hip_runtime.h>
#include <math.h>

// Problem constants (from reference)
#define Bb   8
#define Qq   64
#define Kk   256
#define Dd   256
#define Nn   (Bb * Qq)          // 512
#define GNi  0.0625f            // 1/GN
#define EPSf 1e-5f

// ---------------------------------------------------------------------------
// 64-lane wave reduction (sum), result broadcast to all lanes
__device__ __forceinline__ float wred(float x) {
#pragma unroll
    for (int off = 32; off > 0; off >>= 1)
        x += __shfl_xor(x, off, 64);
    return x;
}

// ---------------------------------------------------------------------------
// 64x64 GEMM tile core, R regions sharing one A tile. 256 threads.
// A: 64 rows, leading dim lda. B_r: K x 256 weight matrices, col window bn.
// acc[r][i*4+j]: thread (ty,tx) owns rows ty*4+i, cols tx*4+j.
// As k-major [16][68]; Ws_r [16][68]. Register-prefetched staging.
template<int R>
__device__ __forceinline__ void gemm64(
    const float* __restrict__ A, int lda,
    const float* __restrict__ B0, const float* __restrict__ B1,
    const float* __restrict__ B2, const float* __restrict__ B3,
    int bn, int Kc, float (&acc)[R][16], float* As, float* Ws)
{
    const int tid = threadIdx.x;
    const int aRow = tid >> 2, aCol = (tid & 3) * 4;
    const int wr = tid >> 4, wcb = (tid & 15) * 4;
    const int ty = tid >> 4, tx = tid & 15;
    const float* Bp[4] = {B0, B1, B2, B3};

    float4 rA = *(const float4*)(A + (size_t)aRow * lda + aCol);
    float4 rW[R];
#pragma unroll
    for (int r = 0; r < R; ++r)
        rW[r] = *(const float4*)(Bp[r] + (size_t)wr * 256 + bn + wcb);

    for (int k0 = 0; k0 < Kc; k0 += 16) {
        __syncthreads();
        As[(aCol + 0) * 68 + aRow] = rA.x;
        As[(aCol + 1) * 68 + aRow] = rA.y;
        As[(aCol + 2) * 68 + aRow] = rA.z;
        As[(aCol + 3) * 68 + aRow] = rA.w;
#pragma unroll
        for (int r = 0; r < R; ++r)
            *(float4*)&Ws[r * 1088 + wr * 68 + wcb] = rW[r];
        __syncthreads();
        if (k0 + 16 < Kc) {
            rA = *(const float4*)(A + (size_t)aRow * lda + k0 + 16 + aCol);
#pragma unroll
            for (int r = 0; r < R; ++r)
                rW[r] = *(const float4*)(Bp[r] + (size_t)(k0 + 16 + wr) * 256 + bn + wcb);
        }
#pragma unroll
        for (int kk = 0; kk < 16; ++kk) {
            const float4 a4 = *(const float4*)&As[kk * 68 + ty * 4];
            const float av[4] = {a4.x, a4.y, a4.z, a4.w};
#pragma unroll
            for (int r = 0; r < R; ++r) {
                const float4 b4 = *(const float4*)&Ws[r * 1088 + kk * 68 + tx * 4];
                const float bw[4] = {b4.x, b4.y, b4.z, b4.w};
#pragma unroll
                for (int i = 0; i < 4; ++i)
#pragma unroll
                    for (int j = 0; j < 4; ++j)
                        acc[r][i * 4 + j] = fmaf(av[i], bw[j], acc[r][i * 4 + j]);
            }
        }
    }
}

// ---------------------------------------------------------------------------
// L1 prep: 81 blocks, no inter-dependencies.
//  id <32 : cond = query @ W_cond (512x256)
//  id <48 : Wg = W_gk1 @ W_gk2   (256x256, K=16)
//  id <80 : KVr = keyval @ W_router (2048x4)
//  id ==80: KVq8 = keyval[:,255,:] @ W_q (8x256)
__global__ __launch_bounds__(256) void prep(
    const float* __restrict__ query, const float* __restrict__ keyval,
    const float* __restrict__ W_cond, const float* __restrict__ Wg1,
    const float* __restrict__ Wg2, const float* __restrict__ Wr,
    const float* __restrict__ Wq,
    float* __restrict__ cond, float* __restrict__ Wg,
    float* __restrict__ KVr, float* __restrict__ KVq8)
{
    __shared__ float lds[2 * 1088];
    const int id = blockIdx.x;
    const int tid = threadIdx.x;

    if (id < 48) {
        float acc[1][16] = {};
        const int ty = tid >> 4, tx = tid & 15;
        if (id < 32) {
            const int bm = (id >> 2) * 64, bn = (id & 3) * 64;
            gemm64<1>(query + (size_t)bm * Dd, Dd, W_cond, nullptr, nullptr, nullptr,
                      bn, Dd, acc, lds, lds + 1088);
#pragma unroll
            for (int i = 0; i < 4; ++i)
                *(float4*)&cond[(size_t)(bm + ty * 4 + i) * Dd + bn + tx * 4] =
                    make_float4(acc[0][i * 4 + 0], acc[0][i * 4 + 1],
                                acc[0][i * 4 + 2], acc[0][i * 4 + 3]);
        } else {
            const int id3 = id - 32;
            const int bm = (id3 >> 2) * 64, bn = (id3 & 3) * 64;
            gemm64<1>(Wg1 + (size_t)bm * 16, 16, Wg2, nullptr, nullptr, nullptr,
                      bn, 16, acc, lds, lds + 1088);
#pragma unroll
            for (int i = 0; i < 4; ++i)
                *(float4*)&Wg[(size_t)(bm + ty * 4 + i) * Dd + bn + tx * 4] =
                    make_float4(acc[0][i * 4 + 0], acc[0][i * 4 + 1],
                                acc[0][i * 4 + 2], acc[0][i * 4 + 3]);
        }
        return;
    }
    if (id < 80) {    // KVr: 32 blocks x 256 threads = 8192 = 2048x4
        const int idx = (id - 48) * 256 + tid;
        const int row = idx >> 2, col = idx & 3;
        float a = 0.f;
        for (int k = 0; k < 256; ++k)
            a = fmaf(keyval[(size_t)row * Dd + k], Wr[(size_t)k * 4 + col], a);
        KVr[idx] = a;
        return;
    }
    // KVq8: stage last keyval row of each batch, then dot with W_q col tid
    for (int b8 = 0; b8 < 8; ++b8)
        lds[b8 * 256 + tid] = keyval[((size_t)b8 * Kk + 255) * Dd + tid];
    __syncthreads();
    float a8[8] = {};
    for (int k = 0; k < 256; ++k) {
        const float wq = Wq[(size_t)k * Dd + tid];
#pragma unroll
        for (int b8 = 0; b8 < 8; ++b8)
            a8[b8] = fmaf(lds[b8 * 256 + k], wq, a8[b8]);
    }
    for (int b8 = 0; b8 < 8; ++b8)
        KVq8[b8 * 256 + tid] = a8[b8];
}

// ---------------------------------------------------------------------------
// L2 main: 168 blocks (needs cond, Wg).
//  id <128 : KVi[row][c] = {k,v,pre,0}, 3-region blocks over keyval
//  id <160 : Cbi[n][c] = {q,k,v,pre}, 4-region blocks over cond
//  id <168 : Cr = cond @ W_router (512x4)
__global__ __launch_bounds__(256) void maingemm(
    const float* __restrict__ keyval, const float* __restrict__ cond,
    const float* __restrict__ Wq, const float* __restrict__ Wk,
    const float* __restrict__ Wv, const float* __restrict__ Wg,
    const float* __restrict__ Wr,
    float* __restrict__ KVi, float* __restrict__ Cbi, float* __restrict__ Cr)
{
    __shared__ float lds[5 * 1088];
    const int id = blockIdx.x;
    const int tid = threadIdx.x;
    const int ty = tid >> 4, tx = tid & 15;

    if (id < 128) {
        const int bm = (id >> 2) * 64;
        const int bn = (id & 3) * 64;
        float acc[3][16] = {};
        gemm64<3>(keyval + (size_t)bm * Dd, Dd, Wk, Wv, Wg, nullptr,
                  bn, Dd, acc, lds, lds + 1088);
#pragma unroll
        for (int i = 0; i < 4; ++i) {
            const size_t rowo = (size_t)(bm + ty * 4 + i) * 1024;
#pragma unroll
            for (int j = 0; j < 4; ++j)
                *(float4*)&KVi[rowo + (size_t)(bn + tx * 4 + j) * 4] =
                    make_float4(acc[0][i * 4 + j], acc[1][i * 4 + j],
                                acc[2][i * 4 + j], 0.f);
        }
    } else if (id < 160) {
        const int id2 = id - 128;
        const int bm = (id2 >> 2) * 64;
        const int bn = (id2 & 3) * 64;
        float acc[4][16] = {};
        gemm64<4>(cond + (size_t)bm * Dd, Dd, Wq, Wk, Wv, Wg,
                  bn, Dd, acc, lds, lds + 1088);
#pragma unroll
        for (int i = 0; i < 4; ++i) {
            const size_t rowo = (size_t)(bm + ty * 4 + i) * 1024;
#pragma unroll
            for (int j = 0; j < 4; ++j)
                *(float4*)&Cbi[rowo + (size_t)(bn + tx * 4 + j) * 4] =
                    make_float4(acc[0][i * 4 + j], acc[1][i * 4 + j],
                                acc[2][i * 4 + j], acc[3][i * 4 + j]);
        }
    } else {          // Cr: 8 blocks x 256 = 2048 = 512x4
        const int idx = (id - 160) * 256 + tid;
        const int row = idx >> 2, col = idx & 3;
        float a = 0.f;
        for (int k = 0; k < 256; ++k)
            a = fmaf(cond[(size_t)row * Dd + k], Wr[(size_t)k * 4 + col], a);
        Cr[idx] = a;
    }
}

// ---------------------------------------------------------------------------
// One 16-t tile of the reverse recurrence: phase A from registers (buf),
// phase B wave-local LDS transpose-reduce.
__device__ __forceinline__ void tile_step(
    const float4* buf, int thi, const float* mfs, const float4* wm,
    float ql, float kc, float vc, float pc,
    float& E0, float& E1, float& E2, float& E3, float& E4, float& o,
    float (*Pt)[68], float* sb, int lane, int tl, int qq)
{
    float vreg[16];
#pragma unroll
    for (int i = 0; i < 16; ++i) {
        const int t = thi - i;
        const float mf = mfs[t];
        const float4 kv = buf[i];
        const float kkv = (kv.x + kc) * mf;
        vreg[i] = (kv.y + vc) * mf;
        const float pre = kv.z + pc;
        const float4 w = wm[t];
        const float ls = fminf(pre, 0.f) - __logf(1.f + __expf(-fabsf(pre)));
        float dg = __expf(ls * GNi);
        dg = (mf != 0.f) ? dg : 1.f;
        const float zf = (E0 + w.x * E1) + (w.y * E2 + w.z * E3) + w.w * E4;
        Pt[i][lane] = ql * kkv * zf;
        E0 *= dg;
        E1 *= (w.x > 0.f) ? dg : 1.f;
        E2 *= (w.y > 0.f) ? dg : 1.f;
        E3 *= (w.z > 0.f) ? dg : 1.f;
        E4 *= (w.w > 0.f) ? dg : 1.f;
    }
    __builtin_amdgcn_wave_barrier();
    // s[tl] = sum_c Pt[tl][c]; lane -> (tl = t-idx 0..15, qq = c-16-group)
    float s = 0.f;
#pragma unroll
    for (int r = 0; r < 4; ++r) {
        const float4 p4 = *(const float4*)&Pt[tl][qq * 16 + r * 4];
        s += (p4.x + p4.y) + (p4.z + p4.w);
    }
    s += __shfl_xor(s, 16, 64);
    s += __shfl_xor(s, 32, 64);
    sb[tl] = s;                       // same-value multi-write, benign
    __builtin_amdgcn_wave_barrier();
#pragma unroll
    for (int r = 0; r < 4; ++r) {
        const float4 sv = *(const float4*)&sb[r * 4];
        o = fmaf(sv.x, vreg[r * 4 + 0], o);
        o = fmaf(sv.y, vreg[r * 4 + 1], o);
        o = fmaf(sv.z, vreg[r * 4 + 2], o);
        o = fmaf(sv.w, vreg[r * 4 + 3], o);
    }
}

// ---------------------------------------------------------------------------
// Fused router + recurrence + RMSNorm + W_o projection. One block per n.
// amdgpu_waves_per_eu(2,2): grid gives exactly 2 waves/SIMD, so tell the
// allocator to optimize FOR that occupancy (256-VGPR budget) — keeps the
// 2x16xfloat4 prefetch double-buffer genuinely register-resident instead of
// sinking the loads to their use sites (rounds 4-7: VGPR 56/100/64).
// XCD swizzle: bi -> n = (bi&7)*64 + (bi>>3) for per-batch L2 locality.
__global__ __attribute__((amdgpu_flat_work_group_size(256, 256)))
__attribute__((amdgpu_waves_per_eu(2, 2))) void mom_fused(
    const float4* __restrict__ KVi, const float* __restrict__ KVr,
    const float4* __restrict__ Cbi, const float* __restrict__ Cr,
    const float* __restrict__ KVq8, const float* __restrict__ b_gk2,
    const int* __restrict__ mask, const float* __restrict__ W_o,
    const float* __restrict__ norm_w,
    float* __restrict__ out, float* __restrict__ logits)
{
    __shared__ __align__(16) float4 wm[Kk];
    __shared__ __align__(16) float  mfs[Kk];
    __shared__ __align__(16) float  Ptile[4][16][68];
    __shared__ __align__(16) float  sbuf[4][16];
    __shared__ __align__(16) float  onorm[Dd];

    const int bi = blockIdx.x;
    const int n = (bi & 7) * 64 + (bi >> 3);
    const int b = bi & 7;             // = n >> 6
    const int j = threadIdx.x;
    const int lane = j & 63;
    const int wv = j >> 6;

    // cond-side values (interleaved)
    const float4 c4 = Cbi[(size_t)n * 256 + j];
    const float qc = c4.x, kc = c4.y, vc = c4.z;
    const float pc = c4.w + b_gk2[j];
    const float ql = KVq8[b * 256 + j] + qc;

    // ---- router top-2 for t = j; also stage mask as float
    {
        mfs[j] = (float)mask[b * Kk + j];
        const float4 kvr = *(const float4*)&KVr[(size_t)(b * Kk + j) * 4];
        const float4 cr  = *(const float4*)&Cr[(size_t)n * 4];
        float l[4] = {kvr.x + cr.x, kvr.y + cr.y, kvr.z + cr.z, kvr.w + cr.w};
        *(float4*)(logits + ((size_t)n * Kk + j) * 4) =
            make_float4(l[0], l[1], l[2], l[3]);

        int i1 = 0;
#pragma unroll
        for (int q = 1; q < 4; ++q) if (l[q] > l[i1]) i1 = q;
        int i2 = -1;
#pragma unroll
        for (int q = 0; q < 4; ++q) {
            if (q == i1) continue;
            if (i2 < 0 || l[q] > l[i2]) i2 = q;
        }
        const float mx = fmaxf(l[i1], l[i2]);
        const float e1 = __expf(l[i1] - mx);
        const float e2 = __expf(l[i2] - mx);
        const float inv = 1.f / (e1 + e2);
        float w[4] = {0.f, 0.f, 0.f, 0.f};
        w[i1] = e1 * inv;
        w[i2] = e2 * inv;
        wm[j] = make_float4(w[0], w[1], w[2], w[3]);
    }
    __syncthreads();

    const float4* pkv = KVi + (size_t)b * Kk * 256 + j;

    float E0 = 1.f, E1 = 1.f, E2 = 1.f, E3 = 1.f, E4 = 1.f;
    float o = 0.f;
    const int tl = lane & 15, qq = lane >> 4;

    float4 bufA[16], bufB[16];
#pragma unroll
    for (int i = 0; i < 16; ++i) bufA[i] = pkv[(size_t)(255 - i) * 256];

    for (int p = 0; p < 8; ++p) {
        const int tA = 255 - 32 * p;
        const int tB = tA - 16;
#pragma unroll
        for (int i = 0; i < 16; ++i) bufB[i] = pkv[(size_t)(tB - i) * 256];
        tile_step(bufA, tA, mfs, wm, ql, kc, vc, pc,
                  E0, E1, E2, E3, E4, o, Ptile[wv], sbuf[wv], lane, tl, qq);
        if (p < 7) {
#pragma unroll
            for (int i = 0; i < 16; ++i)
                bufA[i] = pkv[(size_t)(tB - 16 - i) * 256];
        }
        tile_step(bufB, tB, mfs, wm, ql, kc, vc, pc,
                  E0, E1, E2, E3, E4, o, Ptile[wv], sbuf[wv], lane, tl, qq);
    }

    // ---- fused RMSNorm over DV (per head = per wave)
    const float ms = wred(o * o) * (1.0f / 64.0f);
    onorm[j] = o * rsqrtf(ms + EPSf) * norm_w[lane];
    __syncthreads();

    // ---- fused output projection: out[n,j] = onorm . W_o[:,j]
    float acc = 0.f;
#pragma unroll 8
    for (int k = 0; k < Dd; ++k)
        acc = fmaf(onorm[k], W_o[(size_t)k * Dd + j], acc);
    out[(size_t)n * Dd + j] = acc;
}

// ---------------------------------------------------------------------------
extern "C" void kernel_launch(void* const* d_in, const int* in_sizes, int n_in,
                              void* d_out, int out_size, void* d_ws, size_t ws_size,
                              hipStream_t stream)
{
    const float* query    = (const float*)d_in[0];   // (8,64,256)
    const float* keyval   = (const float*)d_in[1];   // (8,256,256)
    const int*   mask     = (const int*)  d_in[2];   // (8,256)
    const float* W_cond   = (const float*)d_in[3];   // (256,256)
    const float* W_q      = (const float*)d_in[4];   // (256,256)
    const float* W_k      = (const float*)d_in[5];   // (256,256)
    const float* W_v      = (const float*)d_in[6];   // (256,256)
    const float* W_gk1    = (const float*)d_in[7];   // (256,16)
    const float* W_gk2    = (const float*)d_in[8];   // (16,256)
    const float* b_gk2    = (const float*)d_in[9];   // (256,)
    const float* W_router = (const float*)d_in[10];  // (256,4)
    const float* norm_w   = (const float*)d_in[11];  // (64,)
    const float* W_o      = (const float*)d_in[12];  // (256,256)

    float* out    = (float*)d_out;        // (8,64,256) = 131072
    float* logits = out + Nn * Dd;        // (N*K, 4)   = 524288

    // workspace layout (floats)
    float* p = (float*)d_ws;
    float* Wg   = p; p += Dd * Dd;                  // 65536
    float* cond = p; p += Nn * Dd;                  // 131072
    float* KVi  = p; p += (size_t)Bb * Kk * 1024;   // 2097152 {k,v,pre,0}
    float* KVr  = p; p += Bb * Kk * 4;              // 8192
    float* Cbi  = p; p += (size_t)Nn * 1024;        // 524288 {q,k,v,pre}
    float* Cr   = p; p += Nn * 4;                   // 2048
    float* KVq8 = p; p += Bb * Dd;                  // 2048

    // L1: cond, Wg, KVr, KVq8 (all independent)
    prep<<<81, dim3(256), 0, stream>>>(
        query, keyval, W_cond, W_gk1, W_gk2, W_router, W_q,
        cond, Wg, KVr, KVq8);

    // L2: KVi (keyval-side, 3 regions/block), Cbi (cond-side, 4 regions), Cr
    maingemm<<<168, dim3(256), 0, stream>>>(
        keyval, cond, W_q, W_k, W_v, Wg, W_router, KVi, Cbi, Cr);

    // L3: router + recurrence + RMSNorm + output projection
    mom_fused<<<Nn, dim3(256), 0, stream>>>(
        (const float4*)KVi, KVr, (const float4*)Cbi, Cr,
        KVq8, b_gk2, mask, W_o, norm_w, out, logits);
}